// Round 1
// baseline (272.262 us; speedup 1.0000x reference)
//
#include <hip/hip_runtime.h>
#include <hip/hip_bf16.h>

// Problem: B=2, T=2048, D=1024, H=16, DH=64
#define BB 2
#define TT 2048
#define DD 1024
#define HH 16
#define DHH 64
#define MM (BB*TT)        // 4096
#define N3 (3*DD)         // 3072

typedef __attribute__((ext_vector_type(8))) short short8;
typedef __attribute__((ext_vector_type(4))) float f32x4;

__device__ __forceinline__ unsigned short f2bf(float f) {
    union { float f; unsigned u; } v; v.f = f;
    unsigned r = v.u + 0x7FFFu + ((v.u >> 16) & 1u);
    return (unsigned short)(r >> 16);
}

// ---------------- cast fp32 -> bf16, vectorized ----------------
__global__ void cast_bf16_kernel(const float* __restrict__ src,
                                 unsigned short* __restrict__ dst, int n8) {
    int i = blockIdx.x * blockDim.x + threadIdx.x;
    int stride = gridDim.x * blockDim.x;
    for (; i < n8; i += stride) {
        const float4* s = reinterpret_cast<const float4*>(src) + (size_t)i * 2;
        float4 a = s[0], b = s[1];
        unsigned short r[8] = {f2bf(a.x), f2bf(a.y), f2bf(a.z), f2bf(a.w),
                               f2bf(b.x), f2bf(b.y), f2bf(b.z), f2bf(b.w)};
        *reinterpret_cast<uint4*>(dst + (size_t)i * 8) = *reinterpret_cast<uint4*>(r);
    }
}

// ---------------- transpose + cast: src[rows][cols] f32 -> dst[cols][rows] bf16 ----------------
__global__ void transpose_cast_kernel(const float* __restrict__ src,
                                      unsigned short* __restrict__ dst,
                                      int rows, int cols) {
    __shared__ float tile[32][33];
    int c0 = blockIdx.x * 32, r0 = blockIdx.y * 32;
    int tx = threadIdx.x, ty = threadIdx.y;   // block (32,8)
#pragma unroll
    for (int i = 0; i < 4; i++) {
        int r = ty + i * 8;
        tile[r][tx] = src[(size_t)(r0 + r) * cols + c0 + tx];
    }
    __syncthreads();
#pragma unroll
    for (int i = 0; i < 4; i++) {
        int r = ty + i * 8;   // col-dim index of src = row of dst tile
        dst[(size_t)(c0 + r) * rows + r0 + tx] = f2bf(tile[tx][r]);
    }
}

// ---------------- GEMM: C[M][N] = A[M][K] * Bt[N][K]^T  (bf16 in, fp32 acc) ----------------
// tile 128x128, BK=32, 256 threads = 4 waves (2x2), each wave 64x64 = 4x4 frags of 16x16
template<int WRITE_BF16>
__global__ __launch_bounds__(256)
void gemm_kernel(const unsigned short* __restrict__ A,
                 const unsigned short* __restrict__ Bt,
                 void* __restrict__ Cout, int M, int N, int K) {
    __shared__ unsigned short As[128][40];
    __shared__ unsigned short Bs[128][40];
    const int tm = blockIdx.y * 128, tn = blockIdx.x * 128;
    const int t = threadIdx.x;
    const int w = t >> 6, lane = t & 63, lo = lane & 15, hi = lane >> 4;
    const int wr = w >> 1, wc = w & 1;
    const int lr = t >> 2;          // 0..63
    const int lc = (t & 3) * 8;     // 0,8,16,24

    f32x4 acc[4][4];
#pragma unroll
    for (int i = 0; i < 4; i++)
#pragma unroll
        for (int j = 0; j < 4; j++) acc[i][j] = (f32x4){0.f, 0.f, 0.f, 0.f};

    for (int k0 = 0; k0 < K; k0 += 32) {
#pragma unroll
        for (int rnd = 0; rnd < 2; rnd++) {
            int r = lr + rnd * 64;
            *reinterpret_cast<uint4*>(&As[r][lc]) =
                *reinterpret_cast<const uint4*>(&A[(size_t)(tm + r) * K + k0 + lc]);
            *reinterpret_cast<uint4*>(&Bs[r][lc]) =
                *reinterpret_cast<const uint4*>(&Bt[(size_t)(tn + r) * K + k0 + lc]);
        }
        __syncthreads();
        short8 af[4], bfr[4];
#pragma unroll
        for (int i = 0; i < 4; i++) {
            af[i]  = *reinterpret_cast<const short8*>(&As[wr * 64 + i * 16 + lo][hi * 8]);
            bfr[i] = *reinterpret_cast<const short8*>(&Bs[wc * 64 + i * 16 + lo][hi * 8]);
        }
#pragma unroll
        for (int i = 0; i < 4; i++)
#pragma unroll
            for (int j = 0; j < 4; j++)
                acc[i][j] = __builtin_amdgcn_mfma_f32_16x16x32_bf16(af[i], bfr[j], acc[i][j], 0, 0, 0);
        __syncthreads();
    }
#pragma unroll
    for (int i = 0; i < 4; i++)
#pragma unroll
        for (int j = 0; j < 4; j++)
#pragma unroll
            for (int r = 0; r < 4; r++) {
                int row = tm + wr * 64 + i * 16 + hi * 4 + r;
                int col = tn + wc * 64 + j * 16 + lo;
                float v = acc[i][j][r];
                if (WRITE_BF16)
                    ((unsigned short*)Cout)[(size_t)row * N + col] = f2bf(v);
                else
                    ((float*)Cout)[(size_t)row * N + col] = v;
            }
}

// ---------------- Flash attention (causal), bf16 MFMA ----------------
// grid (T/128, H, B), 256 threads = 4 waves; wave w owns 32 q-rows.
// qkv: [B*T][3072] bf16 (q: +0, k: +1024, v: +2048, each h*64+dh)
// out: [B*T][1024] bf16, layout [b][t][h][dh]
__global__ __launch_bounds__(256)
void attn_kernel(const unsigned short* __restrict__ qkv,
                 unsigned short* __restrict__ outp) {
    __shared__ unsigned short Plds[4][32][40];
    const int b = blockIdx.z, h = blockIdx.y, qc = blockIdx.x;
    const int t = threadIdx.x;
    const int w = t >> 6, lane = t & 63, lo = lane & 15, hi = lane >> 4;
    const int q0 = qc * 128 + w * 32;
    const unsigned short* base = qkv + (size_t)b * TT * N3;

    // Q fragments (loop-invariant)
    short8 aq[2][2];
#pragma unroll
    for (int mi = 0; mi < 2; mi++)
#pragma unroll
        for (int ks = 0; ks < 2; ks++)
            aq[mi][ks] = *reinterpret_cast<const short8*>(
                &base[(size_t)(q0 + mi * 16 + lo) * N3 + h * 64 + ks * 32 + hi * 8]);

    f32x4 o[2][4];
    float mrow[2][4], lrow[2][4];
#pragma unroll
    for (int mi = 0; mi < 2; mi++) {
#pragma unroll
        for (int ni = 0; ni < 4; ni++) o[mi][ni] = (f32x4){0.f, 0.f, 0.f, 0.f};
#pragma unroll
        for (int r = 0; r < 4; r++) { mrow[mi][r] = -1e30f; lrow[mi][r] = 0.f; }
    }
    const float sc = 0.125f * 1.44269504088896f;   // 1/sqrt(64) * log2(e)

    for (int kvb = 0; kvb < q0 + 32; kvb += 32) {
        // K^T fragments
        short8 kf[2][2];
#pragma unroll
        for (int ni = 0; ni < 2; ni++)
#pragma unroll
            for (int ks = 0; ks < 2; ks++)
                kf[ni][ks] = *reinterpret_cast<const short8*>(
                    &base[(size_t)(kvb + ni * 16 + lo) * N3 + 1024 + h * 64 + ks * 32 + hi * 8]);
        // S = Q K^T
        f32x4 s[2][2];
#pragma unroll
        for (int mi = 0; mi < 2; mi++)
#pragma unroll
            for (int ni = 0; ni < 2; ni++) {
                s[mi][ni] = (f32x4){0.f, 0.f, 0.f, 0.f};
#pragma unroll
                for (int ks = 0; ks < 2; ks++)
                    s[mi][ni] = __builtin_amdgcn_mfma_f32_16x16x32_bf16(aq[mi][ks], kf[ni][ks], s[mi][ni], 0, 0, 0);
            }
        // scale + causal mask
#pragma unroll
        for (int mi = 0; mi < 2; mi++)
#pragma unroll
            for (int ni = 0; ni < 2; ni++)
#pragma unroll
                for (int r = 0; r < 4; r++) {
                    int row = q0 + mi * 16 + hi * 4 + r;
                    int col = kvb + ni * 16 + lo;
                    float v = s[mi][ni][r] * sc;
                    s[mi][ni][r] = (col <= row) ? v : -1e30f;
                }
        // row max (reduce over lo lanes), online rescale
        float mnew[2][4], alpha[2][4];
#pragma unroll
        for (int mi = 0; mi < 2; mi++)
#pragma unroll
            for (int r = 0; r < 4; r++) {
                float v = fmaxf(s[mi][0][r], s[mi][1][r]);
                v = fmaxf(v, __shfl_xor(v, 1));
                v = fmaxf(v, __shfl_xor(v, 2));
                v = fmaxf(v, __shfl_xor(v, 4));
                v = fmaxf(v, __shfl_xor(v, 8));
                float mn = fmaxf(mrow[mi][r], v);
                mnew[mi][r] = mn;
                alpha[mi][r] = exp2f(mrow[mi][r] - mn);
                mrow[mi][r] = mn;
            }
        // P = exp2(S - m) ; store bf16 to per-wave LDS ; row sums
#pragma unroll
        for (int mi = 0; mi < 2; mi++)
#pragma unroll
            for (int ni = 0; ni < 2; ni++)
#pragma unroll
                for (int r = 0; r < 4; r++) {
                    float p = exp2f(s[mi][ni][r] - mnew[mi][r]);
                    s[mi][ni][r] = p;
                    Plds[w][mi * 16 + hi * 4 + r][ni * 16 + lo] = f2bf(p);
                }
#pragma unroll
        for (int mi = 0; mi < 2; mi++)
#pragma unroll
            for (int r = 0; r < 4; r++) {
                float ps = s[mi][0][r] + s[mi][1][r];
                ps += __shfl_xor(ps, 1);
                ps += __shfl_xor(ps, 2);
                ps += __shfl_xor(ps, 4);
                ps += __shfl_xor(ps, 8);
                lrow[mi][r] = lrow[mi][r] * alpha[mi][r] + ps;
            }
        // rescale O
#pragma unroll
        for (int mi = 0; mi < 2; mi++)
#pragma unroll
            for (int ni = 0; ni < 4; ni++)
#pragma unroll
                for (int r = 0; r < 4; r++)
                    o[mi][ni][r] *= alpha[mi][r];
        // compiler memory barrier: keep P LDS writes before reads (same-wave DS is in-order)
        asm volatile("" ::: "memory");
        // P as A-fragments
        short8 pa[2];
#pragma unroll
        for (int mi = 0; mi < 2; mi++)
            pa[mi] = *reinterpret_cast<const short8*>(&Plds[w][mi * 16 + lo][hi * 8]);
        asm volatile("" ::: "memory");
        // V fragments + PV
#pragma unroll
        for (int ni = 0; ni < 4; ni++) {
            short8 vf;
#pragma unroll
            for (int j = 0; j < 8; j++)
                vf[j] = (short)base[(size_t)(kvb + hi * 8 + j) * N3 + 2048 + h * 64 + ni * 16 + lo];
#pragma unroll
            for (int mi = 0; mi < 2; mi++)
                o[mi][ni] = __builtin_amdgcn_mfma_f32_16x16x32_bf16(pa[mi], vf, o[mi][ni], 0, 0, 0);
        }
    }
    // normalize + write (bf16, [b][t][h][dh])
#pragma unroll
    for (int mi = 0; mi < 2; mi++)
#pragma unroll
        for (int ni = 0; ni < 4; ni++)
#pragma unroll
            for (int r = 0; r < 4; r++) {
                int row = q0 + mi * 16 + hi * 4 + r;
                float v = o[mi][ni][r] / lrow[mi][r];
                outp[(size_t)(b * TT + row) * DD + h * 64 + ni * 16 + lo] = f2bf(v);
            }
}

extern "C" void kernel_launch(void* const* d_in, const int* in_sizes, int n_in,
                              void* d_out, int out_size, void* d_ws, size_t ws_size,
                              hipStream_t stream) {
    const float* x     = (const float*)d_in[0];   // [4096][1024]
    const float* Wqkv  = (const float*)d_in[1];   // [1024][3072]
    const float* Wproj = (const float*)d_in[2];   // [1024][1024]
    float* out = (float*)d_out;                    // [4096][1024] fp32

    // workspace layout (ushorts)
    unsigned short* xb     = (unsigned short*)d_ws;            // 4096*1024
    unsigned short* wqkvt  = xb + (size_t)MM * DD;             // 3072*1024
    unsigned short* wprojt = wqkvt + (size_t)N3 * DD;          // 1024*1024
    unsigned short* qkv    = wprojt + (size_t)DD * DD;         // 4096*3072
    unsigned short* attout = qkv + (size_t)MM * N3;            // 4096*1024
    size_t need = ((size_t)MM * DD + (size_t)N3 * DD + (size_t)DD * DD +
                   (size_t)MM * N3 + (size_t)MM * DD) * 2;
    if (ws_size < need) return;   // insufficient scratch

    cast_bf16_kernel<<<1024, 256, 0, stream>>>(x, xb, MM * DD / 8);
    transpose_cast_kernel<<<dim3(N3 / 32, DD / 32), dim3(32, 8), 0, stream>>>(Wqkv, wqkvt, DD, N3);
    transpose_cast_kernel<<<dim3(DD / 32, DD / 32), dim3(32, 8), 0, stream>>>(Wproj, wprojt, DD, DD);

    gemm_kernel<1><<<dim3(N3 / 128, MM / 128), 256, 0, stream>>>(xb, wqkvt, qkv, MM, N3, DD);

    attn_kernel<<<dim3(TT / 128, HH, BB), 256, 0, stream>>>(qkv, attout);

    gemm_kernel<0><<<dim3(DD / 128, MM / 128), 256, 0, stream>>>(attout, wprojt, out, MM, DD, DD);
}

// Round 2
// 212.971 us; speedup vs baseline: 1.2784x; 1.2784x over previous
//
#include <hip/hip_runtime.h>
#include <hip/hip_bf16.h>

// Problem: B=2, T=2048, D=1024, H=16, DH=64
#define BB 2
#define TT 2048
#define DD 1024
#define HH 16
#define MM (BB*TT)        // 4096
#define N3 (3*DD)         // 3072

typedef __attribute__((ext_vector_type(8))) short short8;
typedef __attribute__((ext_vector_type(4))) float f32x4;

#define GLDS16(g, l) __builtin_amdgcn_global_load_lds( \
    (const __attribute__((address_space(1))) void*)(g), \
    (__attribute__((address_space(3))) void*)(l), 16, 0, 0)

__device__ __forceinline__ unsigned short f2bf(float f) {
    union { float f; unsigned u; } v; v.f = f;
    unsigned r = v.u + 0x7FFFu + ((v.u >> 16) & 1u);
    return (unsigned short)(r >> 16);
}

// ---------------- cast fp32 -> bf16, vectorized ----------------
__global__ void cast_bf16_kernel(const float* __restrict__ src,
                                 unsigned short* __restrict__ dst, int n8) {
    int i = blockIdx.x * blockDim.x + threadIdx.x;
    int stride = gridDim.x * blockDim.x;
    for (; i < n8; i += stride) {
        const float4* s = reinterpret_cast<const float4*>(src) + (size_t)i * 2;
        float4 a = s[0], b = s[1];
        unsigned short r[8] = {f2bf(a.x), f2bf(a.y), f2bf(a.z), f2bf(a.w),
                               f2bf(b.x), f2bf(b.y), f2bf(b.z), f2bf(b.w)};
        *reinterpret_cast<uint4*>(dst + (size_t)i * 8) = *reinterpret_cast<uint4*>(r);
    }
}

// ---------------- transpose + cast: src[rows][cols] f32 -> dst[cols][rows] bf16 ----------------
__global__ void transpose_cast_kernel(const float* __restrict__ src,
                                      unsigned short* __restrict__ dst,
                                      int rows, int cols) {
    __shared__ float tile[32][33];
    int c0 = blockIdx.x * 32, r0 = blockIdx.y * 32;
    int tx = threadIdx.x, ty = threadIdx.y;   // block (32,8)
#pragma unroll
    for (int i = 0; i < 4; i++) {
        int r = ty + i * 8;
        tile[r][tx] = src[(size_t)(r0 + r) * cols + c0 + tx];
    }
    __syncthreads();
#pragma unroll
    for (int i = 0; i < 4; i++) {
        int r = ty + i * 8;
        dst[(size_t)(c0 + r) * rows + r0 + tx] = f2bf(tile[tx][r]);
    }
}

// ---------------- GEMM (m97 structure): C[M][N] = A[M][K] * Bt[N][K]^T ----------------
// 128x128 tile, BK=64, 256 threads = 4 waves (2x2), global_load_lds staging, linear LDS
template<int WRITE_BF16>
__global__ __launch_bounds__(256)
void gemm_kernel(const unsigned short* __restrict__ A,
                 const unsigned short* __restrict__ Bt,
                 void* __restrict__ Cout, int M, int N, int K) {
    __shared__ unsigned short As[128][64];
    __shared__ unsigned short Bs[128][64];
    const int tm = blockIdx.y * 128, tn = blockIdx.x * 128;
    const int t = threadIdx.x;
    const int w = t >> 6, lane = t & 63, lo = lane & 15, hi = lane >> 4;
    const int wr = w >> 1, wc = w & 1;
    const int srow = w * 32 + (lane >> 3);   // staging row (this wave covers 32 rows)
    const int scol = (lane & 7) * 8;         // staging col (ushort)

    f32x4 acc[4][4];
#pragma unroll
    for (int i = 0; i < 4; i++)
#pragma unroll
        for (int j = 0; j < 4; j++) acc[i][j] = (f32x4){0.f, 0.f, 0.f, 0.f};

    const unsigned short* ga = &A[(size_t)(tm + srow) * K + scol];
    const unsigned short* gb = &Bt[(size_t)(tn + srow) * K + scol];

    for (int k0 = 0; k0 < K; k0 += 64) {
        __syncthreads();   // previous iter's frag reads done before overwrite
#pragma unroll
        for (int i = 0; i < 4; i++) {
            GLDS16(ga + (size_t)(i * 8) * K + k0, &As[w * 32 + i * 8][0]);
            GLDS16(gb + (size_t)(i * 8) * K + k0, &Bs[w * 32 + i * 8][0]);
        }
        __syncthreads();   // vmcnt(0) drain + barrier

        short8 af[4][2], bf[4][2];
#pragma unroll
        for (int i = 0; i < 4; i++)
#pragma unroll
            for (int ks = 0; ks < 2; ks++) {
                af[i][ks] = *reinterpret_cast<const short8*>(&As[wr * 64 + i * 16 + lo][ks * 32 + hi * 8]);
                bf[i][ks] = *reinterpret_cast<const short8*>(&Bs[wc * 64 + i * 16 + lo][ks * 32 + hi * 8]);
            }
#pragma unroll
        for (int ks = 0; ks < 2; ks++)
#pragma unroll
            for (int i = 0; i < 4; i++)
#pragma unroll
                for (int j = 0; j < 4; j++)
                    acc[i][j] = __builtin_amdgcn_mfma_f32_16x16x32_bf16(af[i][ks], bf[j][ks], acc[i][j], 0, 0, 0);
    }
#pragma unroll
    for (int i = 0; i < 4; i++)
#pragma unroll
        for (int j = 0; j < 4; j++)
#pragma unroll
            for (int r = 0; r < 4; r++) {
                int row = tm + wr * 64 + i * 16 + hi * 4 + r;
                int col = tn + wc * 64 + j * 16 + lo;
                float v = acc[i][j][r];
                if (WRITE_BF16)
                    ((unsigned short*)Cout)[(size_t)row * N + col] = f2bf(v);
                else
                    ((float*)Cout)[(size_t)row * N + col] = v;
            }
}

// ---------------- Flash attention (causal), LDS-staged K/V, KV tile = 64 ----------------
// grid (H, T/128, B), 256 threads = 4 waves; wave w owns q rows [qc*128+w*32, +32)
__global__ __launch_bounds__(256)
void attn_kernel(const unsigned short* __restrict__ qkv,
                 unsigned short* __restrict__ outp) {
    __shared__ unsigned short Ks[64][72];       // K[kv][dh], padded
    __shared__ unsigned short Vt[64][68];       // V^T[dh][kv], padded
    __shared__ unsigned short Plds[4][32][72];  // per-wave P[q][kv]

    const int b = blockIdx.z, h = blockIdx.x;
    const int qc = (TT / 128 - 1) - blockIdx.y;   // heavy blocks first
    const int t = threadIdx.x;
    const int w = t >> 6, lane = t & 63, lo = lane & 15, hi = lane >> 4;
    const int q0 = qc * 128 + w * 32;
    const unsigned short* base = qkv + (size_t)b * TT * N3;

    // Q fragments (loop-invariant)
    short8 aq[2][2];
#pragma unroll
    for (int mi = 0; mi < 2; mi++)
#pragma unroll
        for (int ks = 0; ks < 2; ks++)
            aq[mi][ks] = *reinterpret_cast<const short8*>(
                &base[(size_t)(q0 + mi * 16 + lo) * N3 + h * 64 + ks * 32 + hi * 8]);

    f32x4 o[2][4];
    float mrow[2][4], lrow[2][4];
#pragma unroll
    for (int mi = 0; mi < 2; mi++) {
#pragma unroll
        for (int ni = 0; ni < 4; ni++) o[mi][ni] = (f32x4){0.f, 0.f, 0.f, 0.f};
#pragma unroll
        for (int r = 0; r < 4; r++) { mrow[mi][r] = -1e30f; lrow[mi][r] = 0.f; }
    }
    const float sc = 0.125f * 1.44269504088896f;   // 1/sqrt(64) * log2(e)

    // staging indices
    const int kr = t >> 2, kc = (t & 3) * 16;      // K: 64 rows x 64 cols, 32B/thread
    const int va = (t & 7) * 8, vr = (t >> 3) * 2; // V: transpose, 2 rows x 8 cols/thread

    const int kvEnd = qc * 128 + 128;
    for (int kvb = 0; kvb < kvEnd; kvb += 64) {
        // ---- issue global loads early (hide HBM latency under barrier wait) ----
        const unsigned short* gk = &base[(size_t)(kvb + kr) * N3 + DD + h * 64 + kc];
        uint4 k0v = *reinterpret_cast<const uint4*>(gk);
        uint4 k1v = *reinterpret_cast<const uint4*>(gk + 8);
        const unsigned short* gv = &base[(size_t)(kvb + vr) * N3 + 2 * DD + h * 64 + va];
        uint4 v0 = *reinterpret_cast<const uint4*>(gv);
        uint4 v1 = *reinterpret_cast<const uint4*>(gv + N3);

        __syncthreads();   // everyone done reading previous tile
        *reinterpret_cast<uint4*>(&Ks[kr][kc]) = k0v;
        *reinterpret_cast<uint4*>(&Ks[kr][kc + 8]) = k1v;
        {
            const unsigned short* e0 = (const unsigned short*)&v0;
            const unsigned short* e1 = (const unsigned short*)&v1;
#pragma unroll
            for (int j = 0; j < 8; j++) {
                unsigned int pk = (unsigned int)e0[j] | ((unsigned int)e1[j] << 16);
                *reinterpret_cast<unsigned int*>(&Vt[va + j][vr]) = pk;
            }
        }
        __syncthreads();   // tile staged

        if (kvb <= q0 + 31) {   // wave-uniform causal skip
            // ---- S = Q K^T ----
            f32x4 s[2][4];
#pragma unroll
            for (int ni = 0; ni < 4; ni++) {
                short8 kf0 = *reinterpret_cast<const short8*>(&Ks[ni * 16 + lo][hi * 8]);
                short8 kf1 = *reinterpret_cast<const short8*>(&Ks[ni * 16 + lo][32 + hi * 8]);
#pragma unroll
                for (int mi = 0; mi < 2; mi++) {
                    f32x4 a = (f32x4){0.f, 0.f, 0.f, 0.f};
                    a = __builtin_amdgcn_mfma_f32_16x16x32_bf16(aq[mi][0], kf0, a, 0, 0, 0);
                    a = __builtin_amdgcn_mfma_f32_16x16x32_bf16(aq[mi][1], kf1, a, 0, 0, 0);
                    s[mi][ni] = a;
                }
            }
            // ---- scale (+ mask only on the diagonal tile) ----
            if (kvb + 63 > q0) {
#pragma unroll
                for (int mi = 0; mi < 2; mi++)
#pragma unroll
                    for (int ni = 0; ni < 4; ni++)
#pragma unroll
                        for (int r = 0; r < 4; r++) {
                            int row = q0 + mi * 16 + hi * 4 + r;
                            int col = kvb + ni * 16 + lo;
                            float v = s[mi][ni][r] * sc;
                            s[mi][ni][r] = (col <= row) ? v : -1e30f;
                        }
            } else {
#pragma unroll
                for (int mi = 0; mi < 2; mi++)
#pragma unroll
                    for (int ni = 0; ni < 4; ni++)
#pragma unroll
                        for (int r = 0; r < 4; r++)
                            s[mi][ni][r] *= sc;
            }
            // ---- online softmax: row max, rescale ----
            float mnew[2][4], al[2][4];
#pragma unroll
            for (int mi = 0; mi < 2; mi++)
#pragma unroll
                for (int r = 0; r < 4; r++) {
                    float v = fmaxf(fmaxf(s[mi][0][r], s[mi][1][r]),
                                    fmaxf(s[mi][2][r], s[mi][3][r]));
                    v = fmaxf(v, __shfl_xor(v, 1));
                    v = fmaxf(v, __shfl_xor(v, 2));
                    v = fmaxf(v, __shfl_xor(v, 4));
                    v = fmaxf(v, __shfl_xor(v, 8));
                    float mn = fmaxf(mrow[mi][r], v);
                    mnew[mi][r] = mn;
                    al[mi][r] = exp2f(mrow[mi][r] - mn);
                    mrow[mi][r] = mn;
                }
            // ---- P = exp2(S-m): to LDS (bf16) + row sums ----
#pragma unroll
            for (int mi = 0; mi < 2; mi++)
#pragma unroll
                for (int ni = 0; ni < 4; ni++)
#pragma unroll
                    for (int r = 0; r < 4; r++) {
                        float p = exp2f(s[mi][ni][r] - mnew[mi][r]);
                        s[mi][ni][r] = p;
                        Plds[w][mi * 16 + hi * 4 + r][ni * 16 + lo] = f2bf(p);
                    }
#pragma unroll
            for (int mi = 0; mi < 2; mi++)
#pragma unroll
                for (int r = 0; r < 4; r++) {
                    float ps = (s[mi][0][r] + s[mi][1][r]) + (s[mi][2][r] + s[mi][3][r]);
                    ps += __shfl_xor(ps, 1);
                    ps += __shfl_xor(ps, 2);
                    ps += __shfl_xor(ps, 4);
                    ps += __shfl_xor(ps, 8);
                    lrow[mi][r] = lrow[mi][r] * al[mi][r] + ps;
                }
            // ---- rescale O ----
#pragma unroll
            for (int mi = 0; mi < 2; mi++)
#pragma unroll
                for (int ni = 0; ni < 4; ni++)
#pragma unroll
                    for (int r = 0; r < 4; r++)
                        o[mi][ni][r] *= al[mi][r];
            // ---- PV ----
            asm volatile("" ::: "memory");
            short8 pa[2][2];
#pragma unroll
            for (int mi = 0; mi < 2; mi++)
#pragma unroll
                for (int ks = 0; ks < 2; ks++)
                    pa[mi][ks] = *reinterpret_cast<const short8*>(
                        &Plds[w][mi * 16 + lo][ks * 32 + hi * 8]);
            asm volatile("" ::: "memory");
#pragma unroll
            for (int ni = 0; ni < 4; ni++) {
#pragma unroll
                for (int ks = 0; ks < 2; ks++) {
                    union { unsigned int u[4]; short8 s8; } vv;
#pragma unroll
                    for (int dw = 0; dw < 4; dw++)
                        vv.u[dw] = *reinterpret_cast<const unsigned int*>(
                            &Vt[ni * 16 + lo][ks * 32 + hi * 8 + dw * 2]);
#pragma unroll
                    for (int mi = 0; mi < 2; mi++)
                        o[mi][ni] = __builtin_amdgcn_mfma_f32_16x16x32_bf16(pa[mi][ks], vv.s8, o[mi][ni], 0, 0, 0);
                }
            }
        }
    }
    // ---- normalize + write (bf16, [b][t][h][dh]) ----
#pragma unroll
    for (int mi = 0; mi < 2; mi++)
#pragma unroll
        for (int ni = 0; ni < 4; ni++)
#pragma unroll
            for (int r = 0; r < 4; r++) {
                int row = q0 + mi * 16 + hi * 4 + r;
                float v = o[mi][ni][r] / lrow[mi][r];
                outp[(size_t)(b * TT + row) * DD + h * 64 + ni * 16 + lo] = f2bf(v);
            }
}

extern "C" void kernel_launch(void* const* d_in, const int* in_sizes, int n_in,
                              void* d_out, int out_size, void* d_ws, size_t ws_size,
                              hipStream_t stream) {
    const float* x     = (const float*)d_in[0];   // [4096][1024]
    const float* Wqkv  = (const float*)d_in[1];   // [1024][3072]
    const float* Wproj = (const float*)d_in[2];   // [1024][1024]
    float* out = (float*)d_out;                    // [4096][1024] fp32

    unsigned short* xb     = (unsigned short*)d_ws;            // 4096*1024
    unsigned short* wqkvt  = xb + (size_t)MM * DD;             // 3072*1024
    unsigned short* wprojt = wqkvt + (size_t)N3 * DD;          // 1024*1024
    unsigned short* qkv    = wprojt + (size_t)DD * DD;         // 4096*3072
    unsigned short* attout = qkv + (size_t)MM * N3;            // 4096*1024
    size_t need = ((size_t)MM * DD + (size_t)N3 * DD + (size_t)DD * DD +
                   (size_t)MM * N3 + (size_t)MM * DD) * 2;
    if (ws_size < need) return;

    cast_bf16_kernel<<<1024, 256, 0, stream>>>(x, xb, MM * DD / 8);
    transpose_cast_kernel<<<dim3(N3 / 32, DD / 32), dim3(32, 8), 0, stream>>>(Wqkv, wqkvt, DD, N3);
    transpose_cast_kernel<<<dim3(DD / 32, DD / 32), dim3(32, 8), 0, stream>>>(Wproj, wprojt, DD, DD);

    gemm_kernel<1><<<dim3(N3 / 128, MM / 128), 256, 0, stream>>>(xb, wqkvt, qkv, MM, N3, DD);

    attn_kernel<<<dim3(HH, TT / 128, BB), 256, 0, stream>>>(qkv, attout);

    gemm_kernel<0><<<dim3(DD / 128, MM / 128), 256, 0, stream>>>(attout, wprojt, out, MM, DD, DD);
}

// Round 3
// 181.259 us; speedup vs baseline: 1.5021x; 1.1750x over previous
//
#include <hip/hip_runtime.h>
#include <hip/hip_bf16.h>

// Problem: B=2, T=2048, D=1024, H=16, DH=64
#define BB 2
#define TT 2048
#define DD 1024
#define HH 16
#define MM (BB*TT)        // 4096
#define N3 (3*DD)         // 3072

typedef __attribute__((ext_vector_type(8))) short short8;
typedef __attribute__((ext_vector_type(4))) float f32x4;
typedef __attribute__((ext_vector_type(16))) float f32x16;

#define ZERO16 (f32x16){0,0,0,0,0,0,0,0,0,0,0,0,0,0,0,0}

#define GLDS16(g, l) __builtin_amdgcn_global_load_lds( \
    (const __attribute__((address_space(1))) void*)(g), \
    (__attribute__((address_space(3))) void*)(l), 16, 0, 0)

__device__ __forceinline__ unsigned short f2bf(float f) {
    union { float f; unsigned u; } v; v.f = f;
    unsigned r = v.u + 0x7FFFu + ((v.u >> 16) & 1u);
    return (unsigned short)(r >> 16);
}

__device__ __forceinline__ unsigned cvt_pk_bf16(float lo, float hi) {
    unsigned r;
    asm("v_cvt_pk_bf16_f32 %0, %1, %2" : "=v"(r) : "v"(lo), "v"(hi));
    return r;
}

// ---------------- cast fp32 -> bf16, vectorized ----------------
__global__ void cast_bf16_kernel(const float* __restrict__ src,
                                 unsigned short* __restrict__ dst, int n8) {
    int i = blockIdx.x * blockDim.x + threadIdx.x;
    int stride = gridDim.x * blockDim.x;
    for (; i < n8; i += stride) {
        const float4* s = reinterpret_cast<const float4*>(src) + (size_t)i * 2;
        float4 a = s[0], b = s[1];
        unsigned short r[8] = {f2bf(a.x), f2bf(a.y), f2bf(a.z), f2bf(a.w),
                               f2bf(b.x), f2bf(b.y), f2bf(b.z), f2bf(b.w)};
        *reinterpret_cast<uint4*>(dst + (size_t)i * 8) = *reinterpret_cast<uint4*>(r);
    }
}

// ---------------- transpose + cast: src[rows][cols] f32 -> dst[cols][rows] bf16 ----------------
__global__ void transpose_cast_kernel(const float* __restrict__ src,
                                      unsigned short* __restrict__ dst,
                                      int rows, int cols) {
    __shared__ float tile[32][33];
    int c0 = blockIdx.x * 32, r0 = blockIdx.y * 32;
    int tx = threadIdx.x, ty = threadIdx.y;   // block (32,8)
#pragma unroll
    for (int i = 0; i < 4; i++) {
        int r = ty + i * 8;
        tile[r][tx] = src[(size_t)(r0 + r) * cols + c0 + tx];
    }
    __syncthreads();
#pragma unroll
    for (int i = 0; i < 4; i++) {
        int r = ty + i * 8;
        dst[(size_t)(c0 + r) * rows + r0 + tx] = f2bf(tile[tx][r]);
    }
}

// ---------------- GEMM (m97 structure): C[M][N] = A[M][K] * Bt[N][K]^T ----------------
template<int WRITE_BF16>
__global__ __launch_bounds__(256)
void gemm_kernel(const unsigned short* __restrict__ A,
                 const unsigned short* __restrict__ Bt,
                 void* __restrict__ Cout, int M, int N, int K) {
    __shared__ unsigned short As[128][64];
    __shared__ unsigned short Bs[128][64];
    const int tm = blockIdx.y * 128, tn = blockIdx.x * 128;
    const int t = threadIdx.x;
    const int w = t >> 6, lane = t & 63, lo = lane & 15, hi = lane >> 4;
    const int wr = w >> 1, wc = w & 1;

    f32x4 acc[4][4];
#pragma unroll
    for (int i = 0; i < 4; i++)
#pragma unroll
        for (int j = 0; j < 4; j++) acc[i][j] = (f32x4){0.f, 0.f, 0.f, 0.f};

    const int srow = w * 32 + (lane >> 3);
    const int scol = (lane & 7) * 8;
    const unsigned short* ga = &A[(size_t)(tm + srow) * K + scol];
    const unsigned short* gb = &Bt[(size_t)(tn + srow) * K + scol];

    for (int k0 = 0; k0 < K; k0 += 64) {
        __syncthreads();
#pragma unroll
        for (int i = 0; i < 4; i++) {
            GLDS16(ga + (size_t)(i * 8) * K + k0, &As[w * 32 + i * 8][0]);
            GLDS16(gb + (size_t)(i * 8) * K + k0, &Bs[w * 32 + i * 8][0]);
        }
        __syncthreads();

        short8 af[4][2], bf[4][2];
#pragma unroll
        for (int i = 0; i < 4; i++)
#pragma unroll
            for (int ks = 0; ks < 2; ks++) {
                af[i][ks] = *reinterpret_cast<const short8*>(&As[wr * 64 + i * 16 + lo][ks * 32 + hi * 8]);
                bf[i][ks] = *reinterpret_cast<const short8*>(&Bs[wc * 64 + i * 16 + lo][ks * 32 + hi * 8]);
            }
#pragma unroll
        for (int ks = 0; ks < 2; ks++)
#pragma unroll
            for (int i = 0; i < 4; i++)
#pragma unroll
                for (int j = 0; j < 4; j++)
                    acc[i][j] = __builtin_amdgcn_mfma_f32_16x16x32_bf16(af[i][ks], bf[j][ks], acc[i][j], 0, 0, 0);
    }
#pragma unroll
    for (int i = 0; i < 4; i++)
#pragma unroll
        for (int j = 0; j < 4; j++)
#pragma unroll
            for (int r = 0; r < 4; r++) {
                int row = tm + wr * 64 + i * 16 + hi * 4 + r;
                int col = tn + wc * 64 + j * 16 + lo;
                float v = acc[i][j][r];
                if (WRITE_BF16)
                    ((unsigned short*)Cout)[(size_t)row * N + col] = f2bf(v);
                else
                    ((float*)Cout)[(size_t)row * N + col] = v;
            }
}

// ---------------- Flash attention, swapped-QK^T 32x32x16, in-register softmax ----------------
// grid (H, T/128, B), 256 threads = 4 waves; wave w owns q rows [qc*128 + w*32, +32)
// Per wave: S^T = K·Q^T via mfma(A=K, B=Q): lane holds q = lane&31, 16 kv rows (C-layout).
__global__ __launch_bounds__(256)
void attn_kernel(const unsigned short* __restrict__ qkv,
                 unsigned short* __restrict__ outp) {
    __shared__ unsigned short Ks[2][64][72];   // K[kv][dh]
    __shared__ unsigned short Vt[2][64][72];   // V^T[dh][kv]

    const int b = blockIdx.z, h = blockIdx.x;
    const int qc = (TT / 128 - 1) - blockIdx.y;   // heavy blocks first
    const int t = threadIdx.x;
    const int w = t >> 6, l = t & 63, ql = l & 31, hi8 = l >> 5;
    const int q0 = qc * 128 + w * 32;
    const unsigned short* base = qkv + (size_t)b * TT * N3;

    // Q B-fragments (loop-invariant): lane l -> Q[q0+ql][dh = ks*16 + hi8*8 + j]
    short8 bq[4];
#pragma unroll
    for (int ks = 0; ks < 4; ks++)
        bq[ks] = *reinterpret_cast<const short8*>(
            &base[(size_t)(q0 + ql) * N3 + h * 64 + ks * 16 + hi8 * 8]);

    f32x16 o0 = ZERO16, o1 = ZERO16;   // O[q=crow(r,hi8)][dh = ni*32 + ql]
    float m_r = -1e30f, l_r = 0.f;
    const float sc = 0.125f * 1.44269504088896f;   // 1/sqrt(64) * log2(e)

    // staging indices
    const int kr = t >> 2, kc = (t & 3) * 16;      // K: row kr, 32B
    const int va = (t & 15) * 4, vr = (t >> 4) * 4; // V: 4 dh x 4 kv micro-tile

    uint4 ka, kb;
    uint2 vv0, vv1, vv2, vv3;

#define STAGE_LOAD(KVB) { \
    const unsigned short* gk = &base[(size_t)((KVB) + kr) * N3 + DD + h * 64 + kc]; \
    ka = *reinterpret_cast<const uint4*>(gk); \
    kb = *reinterpret_cast<const uint4*>(gk + 8); \
    const unsigned short* gv = &base[(size_t)((KVB) + vr) * N3 + 2 * DD + h * 64 + va]; \
    vv0 = *reinterpret_cast<const uint2*>(gv); \
    vv1 = *reinterpret_cast<const uint2*>(gv + N3); \
    vv2 = *reinterpret_cast<const uint2*>(gv + 2 * N3); \
    vv3 = *reinterpret_cast<const uint2*>(gv + 3 * N3); }

#define STAGE_WRITE(BUF) { \
    *reinterpret_cast<uint4*>(&Ks[BUF][kr][kc]) = ka; \
    *reinterpret_cast<uint4*>(&Ks[BUF][kr][kc + 8]) = kb; \
    const unsigned short* e0 = (const unsigned short*)&vv0; \
    const unsigned short* e1 = (const unsigned short*)&vv1; \
    const unsigned short* e2 = (const unsigned short*)&vv2; \
    const unsigned short* e3 = (const unsigned short*)&vv3; \
    _Pragma("unroll") \
    for (int j = 0; j < 4; j++) { \
        uint2 pk; \
        pk.x = (unsigned)e0[j] | ((unsigned)e1[j] << 16); \
        pk.y = (unsigned)e2[j] | ((unsigned)e3[j] << 16); \
        *reinterpret_cast<uint2*>(&Vt[BUF][va + j][vr]) = pk; \
    } }

    const int kvEnd = qc * 128 + 128;
    STAGE_LOAD(0);
    STAGE_WRITE(0);

    int it = 0;
    for (int kvb = 0; kvb < kvEnd; kvb += 64, it ^= 1) {
        const bool more = (kvb + 64) < kvEnd;
        if (more) STAGE_LOAD(kvb + 64);
        __syncthreads();   // buf[it] staged; all waves past previous reads

        if (kvb <= q0 + 31) {          // wave-uniform causal skip
            const bool diag = (kvb + 63 > q0);
            const int qg = q0 + ql;
#pragma unroll
            for (int sub = 0; sub < 2; sub++) {
                // K A-frags: lane l -> K[sub*32 + ql][ks*16 + hi8*8 + j]
                short8 ak0 = *reinterpret_cast<const short8*>(&Ks[it][sub * 32 + ql][hi8 * 8]);
                short8 ak1 = *reinterpret_cast<const short8*>(&Ks[it][sub * 32 + ql][16 + hi8 * 8]);
                short8 ak2 = *reinterpret_cast<const short8*>(&Ks[it][sub * 32 + ql][32 + hi8 * 8]);
                short8 ak3 = *reinterpret_cast<const short8*>(&Ks[it][sub * 32 + ql][48 + hi8 * 8]);
                f32x16 sa = ZERO16;
                sa = __builtin_amdgcn_mfma_f32_32x32x16_bf16(ak0, bq[0], sa, 0, 0, 0);
                sa = __builtin_amdgcn_mfma_f32_32x32x16_bf16(ak1, bq[1], sa, 0, 0, 0);
                sa = __builtin_amdgcn_mfma_f32_32x32x16_bf16(ak2, bq[2], sa, 0, 0, 0);
                sa = __builtin_amdgcn_mfma_f32_32x32x16_bf16(ak3, bq[3], sa, 0, 0, 0);

                // scale + mask; lane holds S[q=ql][kv = kvb + sub*32 + crow(r,hi8)]
                float p[16];
#pragma unroll
                for (int r = 0; r < 16; r++) {
                    float v = sa[r] * sc;
                    if (diag) {
                        int kvg = kvb + sub * 32 + ((r & 3) + 8 * (r >> 2) + 4 * hi8);
                        if (kvg > qg) v = -1e30f;
                    }
                    p[r] = v;
                }
                // row max: in-register tree + lane-half combine
                float pmax = fmaxf(
                    fmaxf(fmaxf(fmaxf(p[0], p[1]), fmaxf(p[2], p[3])),
                          fmaxf(fmaxf(p[4], p[5]), fmaxf(p[6], p[7]))),
                    fmaxf(fmaxf(fmaxf(p[8], p[9]), fmaxf(p[10], p[11])),
                          fmaxf(fmaxf(p[12], p[13]), fmaxf(p[14], p[15]))));
                pmax = fmaxf(pmax, __shfl_xor(pmax, 32));

                // T13 defer-max: rescale only when max grew past THR=8 (log2 units)
                if (__any(pmax > m_r + 8.0f)) {
                    float mnew = fmaxf(m_r, pmax);
                    float alpha = exp2f(m_r - mnew);
                    m_r = mnew;
                    l_r *= alpha;
#pragma unroll
                    for (int r = 0; r < 16; r++) {
                        int src = (r & 3) + 8 * (r >> 2) + 4 * hi8;
                        float av = __int_as_float(__builtin_amdgcn_ds_bpermute(
                            src << 2, __float_as_int(alpha)));
                        o0[r] *= av; o1[r] *= av;
                    }
                }
                // P = exp2(S - m), row sum
#pragma unroll
                for (int r = 0; r < 16; r++) p[r] = exp2f(p[r] - m_r);
                float ps = (((p[0] + p[1]) + (p[2] + p[3])) + ((p[4] + p[5]) + (p[6] + p[7])))
                         + (((p[8] + p[9]) + (p[10] + p[11])) + ((p[12] + p[13]) + (p[14] + p[15])));
                ps += __shfl_xor(ps, 32);
                l_r += ps;

                // T12: P -> A-frags via cvt_pk + permlane32_swap
                unsigned c01 = cvt_pk_bf16(p[0], p[1]);
                unsigned c23 = cvt_pk_bf16(p[2], p[3]);
                unsigned c45 = cvt_pk_bf16(p[4], p[5]);
                unsigned c67 = cvt_pk_bf16(p[6], p[7]);
                asm("v_permlane32_swap_b32 %0, %1" : "+v"(c01), "+v"(c45));
                asm("v_permlane32_swap_b32 %0, %1" : "+v"(c23), "+v"(c67));
                unsigned d01 = cvt_pk_bf16(p[8], p[9]);
                unsigned d23 = cvt_pk_bf16(p[10], p[11]);
                unsigned d45 = cvt_pk_bf16(p[12], p[13]);
                unsigned d67 = cvt_pk_bf16(p[14], p[15]);
                asm("v_permlane32_swap_b32 %0, %1" : "+v"(d01), "+v"(d45));
                asm("v_permlane32_swap_b32 %0, %1" : "+v"(d23), "+v"(d67));
                union { unsigned u[4]; short8 s; } f0, f1;
                f0.u[0] = c01; f0.u[1] = c23; f0.u[2] = c45; f0.u[3] = c67;
                f1.u[0] = d01; f1.u[1] = d23; f1.u[2] = d45; f1.u[3] = d67;

                // PV: B-frag lane l -> V[kv = sub*32 + ks*16 + hi8*8 + j][dh = ni*32 + ql]
                short8 bv00 = *reinterpret_cast<const short8*>(&Vt[it][ql][sub * 32 + hi8 * 8]);
                short8 bv01 = *reinterpret_cast<const short8*>(&Vt[it][ql][sub * 32 + 16 + hi8 * 8]);
                short8 bv10 = *reinterpret_cast<const short8*>(&Vt[it][32 + ql][sub * 32 + hi8 * 8]);
                short8 bv11 = *reinterpret_cast<const short8*>(&Vt[it][32 + ql][sub * 32 + 16 + hi8 * 8]);
                o0 = __builtin_amdgcn_mfma_f32_32x32x16_bf16(f0.s, bv00, o0, 0, 0, 0);
                o0 = __builtin_amdgcn_mfma_f32_32x32x16_bf16(f1.s, bv01, o0, 0, 0, 0);
                o1 = __builtin_amdgcn_mfma_f32_32x32x16_bf16(f0.s, bv10, o1, 0, 0, 0);
                o1 = __builtin_amdgcn_mfma_f32_32x32x16_bf16(f1.s, bv11, o1, 0, 0, 0);
            }
        }
        if (more) STAGE_WRITE(it ^ 1);
    }

    // normalize + write: O rows q = crow(r,hi8), cols dh = ni*32 + ql
#pragma unroll
    for (int r = 0; r < 16; r++) {
        int src = (r & 3) + 8 * (r >> 2) + 4 * hi8;
        float lq = __int_as_float(__builtin_amdgcn_ds_bpermute(src << 2, __float_as_int(l_r)));
        float inv = 1.0f / lq;
        size_t off = (size_t)(b * TT + q0 + src) * DD + h * 64 + ql;
        outp[off] = f2bf(o0[r] * inv);
        outp[off + 32] = f2bf(o1[r] * inv);
    }
#undef STAGE_LOAD
#undef STAGE_WRITE
}

extern "C" void kernel_launch(void* const* d_in, const int* in_sizes, int n_in,
                              void* d_out, int out_size, void* d_ws, size_t ws_size,
                              hipStream_t stream) {
    const float* x     = (const float*)d_in[0];   // [4096][1024]
    const float* Wqkv  = (const float*)d_in[1];   // [1024][3072]
    const float* Wproj = (const float*)d_in[2];   // [1024][1024]
    float* out = (float*)d_out;                    // [4096][1024] fp32

    unsigned short* xb     = (unsigned short*)d_ws;            // 4096*1024
    unsigned short* wqkvt  = xb + (size_t)MM * DD;             // 3072*1024
    unsigned short* wprojt = wqkvt + (size_t)N3 * DD;          // 1024*1024
    unsigned short* qkv    = wprojt + (size_t)DD * DD;         // 4096*3072
    unsigned short* attout = qkv + (size_t)MM * N3;            // 4096*1024
    size_t need = ((size_t)MM * DD + (size_t)N3 * DD + (size_t)DD * DD +
                   (size_t)MM * N3 + (size_t)MM * DD) * 2;
    if (ws_size < need) return;

    cast_bf16_kernel<<<1024, 256, 0, stream>>>(x, xb, MM * DD / 8);
    transpose_cast_kernel<<<dim3(N3 / 32, DD / 32), dim3(32, 8), 0, stream>>>(Wqkv, wqkvt, DD, N3);
    transpose_cast_kernel<<<dim3(DD / 32, DD / 32), dim3(32, 8), 0, stream>>>(Wproj, wprojt, DD, DD);

    gemm_kernel<1><<<dim3(N3 / 128, MM / 128), 256, 0, stream>>>(xb, wqkvt, qkv, MM, N3, DD);

    attn_kernel<<<dim3(HH, TT / 128, BB), 256, 0, stream>>>(qkv, attout);

    gemm_kernel<0><<<dim3(DD / 128, MM / 128), 256, 0, stream>>>(attout, wprojt, out, MM, DD, DD);
}